// Round 1
// baseline (839.034 us; speedup 1.0000x reference)
//
#include <hip/hip_runtime.h>
#include <math.h>

// Problem constants: N=1024, H=16, D=64, M=64 -> NPAIR = N*H = 16384
#define NPAIR 16384
#define DDIM 64
#define MDIM 64

// Output layout (flat element offsets, return order: V, Si_new, Zi_new, Pi_new)
#define V_OFF   0LL
#define SI_OFF  1048576LL            // NPAIR*MDIM
#define ZI_OFF  68157440LL           // SI_OFF + NPAIR*DDIM*MDIM
#define PI_OFF  69206016LL           // ZI_OFF + NPAIR*DDIM

// ext_vector type so __builtin_nontemporal_{load,store} accepts it
typedef float v4f __attribute__((ext_vector_type(4)));

__global__ __launch_bounds__(256) void rma_kernel(
    const float* __restrict__ query,
    const float* __restrict__ key,
    const float* __restrict__ value,
    const float* __restrict__ Si,
    const float* __restrict__ Zi,
    const float* __restrict__ Pi,
    float* __restrict__ out)
{
    const int pair = blockIdx.x;
    const int tid  = threadIdx.x;

    __shared__ float Qs[DDIM];
    __shared__ float Ks[DDIM];
    __shared__ float Vls[MDIM];
    __shared__ float Vred[16][68];   // pad 68: row stride != multiple of 32 banks
    __shared__ float Zinv;

    const long long vecOff = (long long)pair * DDIM;
    const long long matOff = (long long)pair * (DDIM * MDIM);

    // Each thread: 4 rows (d = td + 16r) x 4 cols (m = tm..tm+3), 16B vector IO.
    // Wave lanes 0..63 tile 4 contiguous rows -> 1KB contiguous per instruction.
    const int tm = (tid & 15) << 2;   // m base: 0,4,...,60
    const int td = tid >> 4;          // 0..15

    // Issue ALL streaming HBM loads first: their ~900cy latency overlaps the
    // phase-1 vector staging + shfl reduction below (before the barrier, the
    // compiler could not hoist these above __syncthreads on its own).
    // nt policy: zero-reuse stream, don't let it allocate/thrash caches.
    long long flat[4];
    v4f piu[4], siu[4];
    #pragma unroll
    for (int r = 0; r < 4; ++r) {
        const int d = td + 16 * r;
        flat[r] = matOff + (long long)(d * MDIM + tm);
        piu[r] = __builtin_nontemporal_load((const v4f*)(Pi + flat[r]));
        siu[r] = __builtin_nontemporal_load((const v4f*)(Si + flat[r]));
    }

    // Stage per-pair vectors + compute normalizer on wave 0
    if (tid < 64) {
        const int d = tid;
        float q  = query[vecOff + d];
        float k  = key[vecOff + d];
        float zi = Zi[vecOff + d];
        // elu(x)+1 == x+1 (x>0) else exp(x)
        float qe = (q > 0.f) ? (q + 1.f) : expf(q);
        float ke = (k > 0.f) ? (k + 1.f) : expf(k);
        float zn = zi + ke;
        Qs[d]  = qe;
        Ks[d]  = ke;
        Vls[d] = value[vecOff + d];        // d doubles as m index here
        __builtin_nontemporal_store(zn, out + ZI_OFF + vecOff + d);  // Zi_new
        float p = qe * zn;
        #pragma unroll
        for (int off = 32; off > 0; off >>= 1)
            p += __shfl_down(p, off, 64);
        if (tid == 0) Zinv = 1.f / (p + 1e-6f);
    }
    __syncthreads();

    float acc[4] = {0.f, 0.f, 0.f, 0.f};
    const float v0 = Vls[tm + 0], v1 = Vls[tm + 1], v2 = Vls[tm + 2], v3 = Vls[tm + 3];
    #pragma unroll
    for (int r = 0; r < 4; ++r) {
        const int d = td + 16 * r;
        const float kd = Ks[d];
        const float qd = Qs[d];
        v4f pn, sn;
        pn.x = 0.9f * piu[r].x - kd * v0;  sn.x = siu[r].x - pn.x;  acc[0] += qd * sn.x;
        pn.y = 0.9f * piu[r].y - kd * v1;  sn.y = siu[r].y - pn.y;  acc[1] += qd * sn.y;
        pn.z = 0.9f * piu[r].z - kd * v2;  sn.z = siu[r].z - pn.z;  acc[2] += qd * sn.z;
        pn.w = 0.9f * piu[r].w - kd * v3;  sn.w = siu[r].w - pn.w;  acc[3] += qd * sn.w;
        __builtin_nontemporal_store(pn, (v4f*)(out + PI_OFF + flat[r]));   // Pi_new
        __builtin_nontemporal_store(sn, (v4f*)(out + SI_OFF + flat[r]));   // Si_new
    }

    // Reduce V over the 16 d-partials per column
    Vred[td][tm + 0] = acc[0];
    Vred[td][tm + 1] = acc[1];
    Vred[td][tm + 2] = acc[2];
    Vred[td][tm + 3] = acc[3];
    __syncthreads();

    if (tid < 64) {
        float s = 0.f;
        #pragma unroll
        for (int t = 0; t < 16; ++t) s += Vred[t][tid];
        out[V_OFF + vecOff + tid] = s * Zinv;   // V
    }
}

extern "C" void kernel_launch(void* const* d_in, const int* in_sizes, int n_in,
                              void* d_out, int out_size, void* d_ws, size_t ws_size,
                              hipStream_t stream)
{
    const float* query = (const float*)d_in[0];
    const float* key   = (const float*)d_in[1];
    const float* value = (const float*)d_in[2];
    const float* Si    = (const float*)d_in[3];
    const float* Zi    = (const float*)d_in[4];
    const float* Pi    = (const float*)d_in[5];
    float* out = (float*)d_out;

    rma_kernel<<<NPAIR, 256, 0, stream>>>(query, key, value, Si, Zi, Pi, out);
}

// Round 3
// 837.816 us; speedup vs baseline: 1.0015x; 1.0015x over previous
//
#include <hip/hip_runtime.h>
#include <math.h>

// Problem constants: N=1024, H=16, D=64, M=64 -> NPAIR = N*H = 16384
#define NPAIR 16384
#define DDIM 64
#define MDIM 64

// Output layout (flat element offsets, return order: V, Si_new, Zi_new, Pi_new)
#define V_OFF   0LL
#define SI_OFF  1048576LL            // NPAIR*MDIM
#define ZI_OFF  68157440LL           // SI_OFF + NPAIR*DDIM*MDIM
#define PI_OFF  69206016LL           // ZI_OFF + NPAIR*DDIM

typedef float v4f __attribute__((ext_vector_type(4)));

// One wave (64 lanes) owns one (n,h) pair end-to-end. No __syncthreads, no LDS:
// all cross-lane movement via wave shuffles. 4 waves/block.
// Per-lane tile: 16 rows (d = td + 4*rr, td = lane>>4 in 0..3, rr = 0..15)
// x 4 cols (m = tm..tm+3, tm = (lane&15)*4). Each load/store instruction
// covers 4 consecutive rows -> 1KB contiguous.
__global__ __launch_bounds__(256) void rma_kernel(
    const float* __restrict__ query,
    const float* __restrict__ key,
    const float* __restrict__ value,
    const float* __restrict__ Si,
    const float* __restrict__ Zi,
    const float* __restrict__ Pi,
    float* __restrict__ out)
{
    const int lane = threadIdx.x & 63;
    const int wv   = threadIdx.x >> 6;
    const int pair = (blockIdx.x << 2) | wv;

    const long long vecOff = (long long)pair * DDIM;
    const long long matOff = (long long)pair * (DDIM * MDIM);

    // Small per-pair vector loads FIRST (vmcnt is in-order: phase-1 then waits
    // only on these four, leaving the 32 streaming loads in flight below).
    const float q  = query[vecOff + lane];
    const float k  = key[vecOff + lane];
    const float zi = Zi[vecOff + lane];
    const float vv = value[vecOff + lane];   // lane doubles as m index

    const int tm = (lane & 15) << 2;  // column base 0,4,...,60
    const int td = lane >> 4;         // 0..3

    // Issue ALL streaming loads up front: 32 x 16B per lane in flight (~32KB
    // per wave) -- far beyond what's needed to cover ~900cy HBM latency even
    // at 2 waves/SIMD. nt: zero-reuse stream, stay out of the caches.
    long long flat[16];
    v4f piu[16], siu[16];
    #pragma unroll
    for (int rr = 0; rr < 16; ++rr) {
        const int d = td + (rr << 2);                       // covers 0..63 once
        flat[rr] = matOff + (long long)(d * MDIM + tm);
        piu[rr] = __builtin_nontemporal_load((const v4f*)(Pi + flat[rr]));
        siu[rr] = __builtin_nontemporal_load((const v4f*)(Si + flat[rr]));
    }

    // elu(x)+1 == x+1 (x>0) else exp(x)
    const float qe = (q > 0.f) ? (q + 1.f) : expf(q);
    const float ke = (k > 0.f) ? (k + 1.f) : expf(k);
    const float zn = zi + ke;
    __builtin_nontemporal_store(zn, out + ZI_OFF + vecOff + lane);   // Zi_new

    // Normalizer: full-wave butterfly; every lane ends with the total.
    float p = qe * zn;
    #pragma unroll
    for (int off = 32; off; off >>= 1) p += __shfl_xor(p, off, 64);
    const float zinv = 1.f / (p + 1e-6f);

    // V broadcast: value[tm+j] lives in lane tm+j of this wave.
    const float v0 = __shfl(vv, tm + 0, 64);
    const float v1 = __shfl(vv, tm + 1, 64);
    const float v2 = __shfl(vv, tm + 2, 64);
    const float v3 = __shfl(vv, tm + 3, 64);

    float acc0 = 0.f, acc1 = 0.f, acc2 = 0.f, acc3 = 0.f;
    #pragma unroll
    for (int rr = 0; rr < 16; ++rr) {
        const int d = td + (rr << 2);
        const float kd = __shfl(ke, d, 64);
        const float qd = __shfl(qe, d, 64);
        v4f pn, sn;
        pn.x = 0.9f * piu[rr].x - kd * v0;  sn.x = siu[rr].x - pn.x;  acc0 += qd * sn.x;
        pn.y = 0.9f * piu[rr].y - kd * v1;  sn.y = siu[rr].y - pn.y;  acc1 += qd * sn.y;
        pn.z = 0.9f * piu[rr].z - kd * v2;  sn.z = siu[rr].z - pn.z;  acc2 += qd * sn.z;
        pn.w = 0.9f * piu[rr].w - kd * v3;  sn.w = siu[rr].w - pn.w;  acc3 += qd * sn.w;
        __builtin_nontemporal_store(pn, (v4f*)(out + PI_OFF + flat[rr]));   // Pi_new
        __builtin_nontemporal_store(sn, (v4f*)(out + SI_OFF + flat[rr]));   // Si_new
    }

    // Fold the 4 td-groups (lane bits 4,5): after these, every lane holds the
    // full 64-row sum for its 4 columns.
    acc0 += __shfl_xor(acc0, 16, 64);  acc0 += __shfl_xor(acc0, 32, 64);
    acc1 += __shfl_xor(acc1, 16, 64);  acc1 += __shfl_xor(acc1, 32, 64);
    acc2 += __shfl_xor(acc2, 16, 64);  acc2 += __shfl_xor(acc2, 32, 64);
    acc3 += __shfl_xor(acc3, 16, 64);  acc3 += __shfl_xor(acc3, 32, 64);

    if (td == 0) {   // lanes 0..15 write 16B each -> full 256B V row
        v4f vout;
        vout.x = acc0 * zinv;
        vout.y = acc1 * zinv;
        vout.z = acc2 * zinv;
        vout.w = acc3 * zinv;
        *(v4f*)(out + V_OFF + vecOff + tm) = vout;   // V
    }
}

extern "C" void kernel_launch(void* const* d_in, const int* in_sizes, int n_in,
                              void* d_out, int out_size, void* d_ws, size_t ws_size,
                              hipStream_t stream)
{
    const float* query = (const float*)d_in[0];
    const float* key   = (const float*)d_in[1];
    const float* value = (const float*)d_in[2];
    const float* Si    = (const float*)d_in[3];
    const float* Zi    = (const float*)d_in[4];
    const float* Pi    = (const float*)d_in[5];
    float* out = (float*)d_out;

    rma_kernel<<<NPAIR / 4, 256, 0, stream>>>(query, key, value, Si, Zi, Pi, out);
}